// Round 3
// baseline (756.940 us; speedup 1.0000x reference)
//
#include <hip/hip_runtime.h>
#include <stdint.h>

// Problem constants: N=262144 rows, C=256 channels, K=256 codes.
#define CCH 256
#define KK  256

typedef int   i32x4 __attribute__((ext_vector_type(4)));
typedef float f32x4 __attribute__((ext_vector_type(4)));
typedef unsigned short u16x4 __attribute__((ext_vector_type(4)));
typedef unsigned short u16x8 __attribute__((ext_vector_type(8)));

// ---------------------------------------------------------------------------
// K0: compress white_table int32 -> uint8 (values are codes in [0,256)).
// ---------------------------------------------------------------------------
__global__ __launch_bounds__(256) void compress_table_kernel(
    const int4* __restrict__ t, uchar4* __restrict__ o, int n4) {
  int i = blockIdx.x * 256 + threadIdx.x;
  if (i < n4) {
    int4 v = t[i];
    o[i] = make_uchar4((unsigned char)v.x, (unsigned char)v.y,
                       (unsigned char)v.z, (unsigned char)v.w);
  }
}

// ---------------------------------------------------------------------------
// K1: transpose + pack.  L,R [N,C] i32 -> LRt [C, nslice] u16 = (l<<8)|r.
// 64n x 256c tile per block.  int4 global loads (1 KB/wave), ds_write_b64
// into an XOR-swizzled u16 tile (col ^= (r>>3)<<2, pitch 260 -> transposed
// reads are 2-way = free), u16x8 (16 B) global stores.
// ---------------------------------------------------------------------------
__global__ __launch_bounds__(256, 4) void transpose_pack_kernel(
    const i32x4* __restrict__ L4, const i32x4* __restrict__ R4,
    unsigned short* __restrict__ LRt, int n0_base, int nslice) {
  __shared__ unsigned short tile[64 * 260];  // 33.3 KB
  const int tn   = blockIdx.x;
  const int gn0  = n0_base + tn * 64;        // first global row of tile
  const int lane = threadIdx.x & 63;
  const int wid  = threadIdx.x >> 6;         // 0..3

  // Phase A: load 64 rows x 256 ch, pack, swizzled LDS write.
#pragma unroll
  for (int p = 0; p < 16; ++p) {
    const int r = p * 4 + wid;
    const size_t gi = (size_t)(gn0 + r) * 64 + lane;
    i32x4 Lv = L4[gi];
    i32x4 Rv = R4[gi];
    u16x4 w;
    w[0] = (unsigned short)((Lv[0] << 8) | Rv[0]);
    w[1] = (unsigned short)((Lv[1] << 8) | Rv[1]);
    w[2] = (unsigned short)((Lv[2] << 8) | Rv[2]);
    w[3] = (unsigned short)((Lv[3] << 8) | Rv[3]);
    const int col = (lane * 4) ^ (((r >> 3) & 7) << 2);
    *(u16x4*)&tile[r * 260 + col] = w;
  }
  __syncthreads();

  // Phase B: per-channel rows out.  8 passes x 32 channels.
#pragma unroll
  for (int pb = 0; pb < 8; ++pb) {
    const int ch = pb * 32 + (threadIdx.x >> 3);
    const int n8 = threadIdx.x & 7;
    u16x8 v;
#pragma unroll
    for (int j = 0; j < 8; ++j) {
      const int r = n8 * 8 + j;
      v[j] = tile[r * 260 + (ch ^ (n8 << 2))];
    }
    *(u16x8*)&LRt[(size_t)ch * nslice + tn * 64 + n8 * 8] = v;
  }
}

// ---------------------------------------------------------------------------
// K2: per-channel code gather, 64 KB table in LDS, 512 threads (16 waves/CU
// at 2 blocks/CU).  One shot: 16384 elements per block, 4 independent u16x8
// loads in flight per thread.
// ---------------------------------------------------------------------------
__global__ __launch_bounds__(512, 4) void code_gather_kernel(
    const unsigned short* __restrict__ LRt, const unsigned char* __restrict__ tab8,
    unsigned char* __restrict__ codes, int nslice) {
  __shared__ unsigned char tabs[KK * KK];  // 64 KB (static max)
  const int c   = blockIdx.x & (CCH - 1); // channel varies fastest -> XCD L2
  const int sub = blockIdx.x >> 8;
  {
    const int4* src = (const int4*)(tab8 + (size_t)c * (KK * KK));
    int4* dst = (int4*)tabs;
#pragma unroll
    for (int i = 0; i < 8; ++i) dst[threadIdx.x + 512 * i] = src[threadIdx.x + 512 * i];
  }
  __syncthreads();
  const size_t base = (size_t)c * nslice + (size_t)sub * 16384;
  const u16x8* __restrict__ in   = (const u16x8*)(LRt + base);
  uint2*       __restrict__ outp = (uint2*)(codes + base);
  u16x8 v0 = in[          threadIdx.x];
  u16x8 v1 = in[ 512 +    threadIdx.x];
  u16x8 v2 = in[1024 +    threadIdx.x];
  u16x8 v3 = in[1536 +    threadIdx.x];
#define PACK8(v, slot)                                                          \
  {                                                                             \
    unsigned lo = (unsigned)tabs[v[0]] | ((unsigned)tabs[v[1]] << 8) |          \
                  ((unsigned)tabs[v[2]] << 16) | ((unsigned)tabs[v[3]] << 24);  \
    unsigned hi = (unsigned)tabs[v[4]] | ((unsigned)tabs[v[5]] << 8) |          \
                  ((unsigned)tabs[v[6]] << 16) | ((unsigned)tabs[v[7]] << 24);  \
    outp[slot * 512 + threadIdx.x] = make_uint2(lo, hi);                        \
  }
  PACK8(v0, 0) PACK8(v1, 1) PACK8(v2, 2) PACK8(v3, 3)
#undef PACK8
}

// ---------------------------------------------------------------------------
// K3: codebook lookup + transpose back.  codes [C, nslice] u8 -> out [N,C]
// f32.  Tile 256n x 16ch: 16 KB codebook + 4.2 KB dword-pitched code tile
// -> 7 blocks/CU.  Codes read as dwords (4 codes/LDS read).  Non-temporal
// stores keep the 268 MB output stream out of L3.
// ---------------------------------------------------------------------------
__global__ __launch_bounds__(256) void codebook_transpose_kernel(
    const unsigned char* __restrict__ codes, const float* __restrict__ cb,
    float* __restrict__ out, int n0_base, int nslice) {
  __shared__ float cbs[16 * KK];        // 16 KB
  __shared__ unsigned ctd[16 * 66];     // 4.2 KB, pitch 66 dwords
  const int ntiles = nslice >> 8;
  const int tn = blockIdx.x % ntiles;
  const int tc = blockIdx.x / ntiles;   // 0..15
  const int c0 = tc * 16;
  {
    const f32x4* cbg = (const f32x4*)(cb + (size_t)c0 * KK);
    f32x4* cbl = (f32x4*)cbs;
#pragma unroll
    for (int i = 0; i < 4; ++i) cbl[threadIdx.x + 256 * i] = cbg[threadIdx.x + 256 * i];
  }
  {
    const int cc = threadIdx.x >> 4, l16 = threadIdx.x & 15;
    const unsigned* row =
        (const unsigned*)(codes + (size_t)(c0 + cc) * nslice + (size_t)tn * 256);
#pragma unroll
    for (int q = 0; q < 4; ++q) ctd[cc * 66 + q * 16 + l16] = row[q * 16 + l16];
  }
  __syncthreads();
  const int cc = threadIdx.x & 15, nn4 = threadIdx.x >> 4;
  const float* cbrow = cbs + cc * KK;
  float* obase = out + (size_t)(n0_base + tn * 256) * CCH + c0 + cc;
#pragma unroll
  for (int p = 0; p < 4; ++p) {
    const int d = p * 16 + nn4;
    const unsigned c4v = ctd[cc * 66 + d];
#pragma unroll
    for (int k = 0; k < 4; ++k) {
      const float val = cbrow[(c4v >> (8 * k)) & 255u];
      __builtin_nontemporal_store(val, obase + (size_t)(d * 4 + k) * CCH);
    }
  }
}

// ---------------------------------------------------------------------------
// Fallback: TA-path gather (round-1 kernel), used only if workspace is tiny.
// ---------------------------------------------------------------------------
#define ROWS_PER_BLOCK 512
#define NGROUPS 16
#define GCH (CCH / NGROUPS)

template <typename TabT>
__global__ __launch_bounds__(256, 8) void gather_kernel(
    const i32x4* __restrict__ left, const i32x4* __restrict__ right,
    const TabT* __restrict__ tab, const float* __restrict__ cb,
    f32x4* __restrict__ out, int nrows) {
  __shared__ float cbs[GCH * KK];
  const int g     = blockIdx.x & (NGROUPS - 1);
  const int chunk = blockIdx.x / NGROUPS;
  const int q     = threadIdx.x & 3;
  const int rsub  = threadIdx.x >> 2;
  {
    const f32x4* cbg = (const f32x4*)(cb + (size_t)(g * GCH) * KK);
    f32x4* cbl = (f32x4*)cbs;
#pragma unroll
    for (int i = 0; i < 4; ++i) cbl[threadIdx.x + i * 256] = cbg[threadIdx.x + i * 256];
  }
  __syncthreads();
  const int cbase  = g * GCH + q * 4;
  const TabT* t0   = tab + (size_t)cbase * (KK * KK);
  const int vecoff = g * 4 + q;
  const float* cq  = cbs + (q * 4) * KK;
  const int rbase = chunk * ROWS_PER_BLOCK;
#pragma unroll
  for (int it = 0; it < ROWS_PER_BLOCK / 32; ++it) {
    const int r0 = rbase + it * 32 + rsub;
    if (r0 >= nrows) break;
    const unsigned v0 = (unsigned)r0 * 64u + (unsigned)vecoff;
    i32x4 L0 = left[v0];
    i32x4 R0 = right[v0];
    unsigned c0 = (unsigned)t0[          (unsigned)(L0[0] * KK + R0[0])];
    unsigned c1 = (unsigned)t0[ 65536u + (unsigned)(L0[1] * KK + R0[1])];
    unsigned c2 = (unsigned)t0[131072u + (unsigned)(L0[2] * KK + R0[2])];
    unsigned c3 = (unsigned)t0[196608u + (unsigned)(L0[3] * KK + R0[3])];
    f32x4 o;
    o[0] = cq[       c0];
    o[1] = cq[KK   + c1];
    o[2] = cq[2*KK + c2];
    o[3] = cq[3*KK + c3];
    out[v0] = o;
  }
}

extern "C" void kernel_launch(void* const* d_in, const int* in_sizes, int n_in,
                              void* d_out, int out_size, void* d_ws, size_t ws_size,
                              hipStream_t stream) {
  const int*   left  = (const int*)d_in[0];
  const int*   right = (const int*)d_in[1];
  const int*   wt    = (const int*)d_in[2];   // [C, K, K] int32
  const float* cb    = (const float*)d_in[3]; // [C, K] float32
  float* out = (float*)d_out;

  const int nrows = in_sizes[0] / CCH;        // 262144
  const int tab_elems = CCH * KK * KK;        // 16,777,216
  const size_t tab_bytes = (size_t)tab_elems; // u8 table = 16 MB

  // Pick smallest slicing S whose workspace fits:
  //   need = 16 MB table + 512*nslice (LRt u16) + 256*nslice (codes u8)
  // Kernel divisibility requires nslice % 16384 == 0.
  int S = 0;
  for (int s = 1; s <= 16; s <<= 1) {
    if (nrows % (s * 16384)) continue;
    size_t need = tab_bytes + (size_t)768 * (size_t)(nrows / s);
    if (need <= ws_size) { S = s; break; }
  }

  if (S) {
    unsigned char* tab8 = (unsigned char*)d_ws;
    int n4 = tab_elems / 4;
    compress_table_kernel<<<n4 / 256, 256, 0, stream>>>(
        (const int4*)wt, (uchar4*)tab8, n4);

    const int nslice = nrows / S;
    unsigned short* LRt = (unsigned short*)((char*)d_ws + tab_bytes);
    unsigned char* codes = (unsigned char*)d_ws + tab_bytes + (size_t)512 * nslice;

    for (int h = 0; h < S; ++h) {
      const int n0 = h * nslice;
      transpose_pack_kernel<<<nslice / 64, 256, 0, stream>>>(
          (const i32x4*)left, (const i32x4*)right, LRt, n0, nslice);
      code_gather_kernel<<<(nslice / 16384) * CCH, 512, 0, stream>>>(
          LRt, tab8, codes, nslice);
      codebook_transpose_kernel<<<(nslice / 256) * 16, 256, 0, stream>>>(
          codes, cb, out, n0, nslice);
    }
  } else if (ws_size >= tab_bytes) {
    unsigned char* tab8 = (unsigned char*)d_ws;
    int n4 = tab_elems / 4;
    compress_table_kernel<<<n4 / 256, 256, 0, stream>>>(
        (const int4*)wt, (uchar4*)tab8, n4);
    const int blocks = ((nrows + ROWS_PER_BLOCK - 1) / ROWS_PER_BLOCK) * NGROUPS;
    gather_kernel<unsigned char><<<blocks, 256, 0, stream>>>(
        (const i32x4*)left, (const i32x4*)right, tab8, cb, (f32x4*)out, nrows);
  } else {
    const int blocks = ((nrows + ROWS_PER_BLOCK - 1) / ROWS_PER_BLOCK) * NGROUPS;
    gather_kernel<int><<<blocks, 256, 0, stream>>>(
        (const i32x4*)left, (const i32x4*)right, wt, cb, (f32x4*)out, nrows);
  }
}

// Round 4
// 709.799 us; speedup vs baseline: 1.0664x; 1.0664x over previous
//
#include <hip/hip_runtime.h>
#include <stdint.h>

// Problem constants: N=262144 rows, C=256 channels, K=256 codes.
#define CCH 256
#define KK  256

typedef int   i32x4 __attribute__((ext_vector_type(4)));
typedef float f32x4 __attribute__((ext_vector_type(4)));
typedef unsigned short u16x4 __attribute__((ext_vector_type(4)));
typedef unsigned short u16x8 __attribute__((ext_vector_type(8)));

// ---------------------------------------------------------------------------
// K0: compress white_table int32 -> uint8.
// ---------------------------------------------------------------------------
__global__ __launch_bounds__(256) void compress_table_kernel(
    const int4* __restrict__ t, uchar4* __restrict__ o, int n4) {
  int i = blockIdx.x * 256 + threadIdx.x;
  if (i < n4) {
    int4 v = t[i];
    o[i] = make_uchar4((unsigned char)v.x, (unsigned char)v.y,
                       (unsigned char)v.z, (unsigned char)v.w);
  }
}

// ---------------------------------------------------------------------------
// K1: transpose + pack.  L,R [N,C] i32 -> LRt [C, nslice] u16 = (l<<8)|r.
// 128n x 256c tile, 512 threads, 66.6 KB LDS -> 2 blocks/CU.
// Loads: 1 KB/wave contiguous.  Stores: 256 B per channel per block (2x
// round-3 segment length -> better DRAM page locality).
// Swizzle: element (r,c) at tile[r*260 + (c ^ (((r>>3)&15)<<2))]; phase-A
// writes and phase-B reads both verified <=2 lanes/bank (free).
// ---------------------------------------------------------------------------
__global__ __launch_bounds__(512, 4) void transpose_pack_kernel(
    const i32x4* __restrict__ L4, const i32x4* __restrict__ R4,
    unsigned short* __restrict__ LRt, int n0_base, int nslice) {
  __shared__ unsigned short tile[128 * 260];  // 66.6 KB
  const int tn  = blockIdx.x;
  const int gn0 = n0_base + tn * 128;

  // Phase A: 128 rows x 64 quads; per wave 1 KB contiguous loads.
#pragma unroll
  for (int p = 0; p < 16; ++p) {
    const int idx = p * 512 + (int)threadIdx.x;
    const int r   = idx >> 6;   // 0..127
    const int cq  = idx & 63;   // quad within row
    const size_t gi = (size_t)(gn0 + r) * 64 + cq;
    i32x4 Lv = L4[gi];
    i32x4 Rv = R4[gi];
    u16x4 w;
    w[0] = (unsigned short)((Lv[0] << 8) | Rv[0]);
    w[1] = (unsigned short)((Lv[1] << 8) | Rv[1]);
    w[2] = (unsigned short)((Lv[2] << 8) | Rv[2]);
    w[3] = (unsigned short)((Lv[3] << 8) | Rv[3]);
    const int col = (cq * 4) ^ (((r >> 3) & 15) << 2);
    *(u16x4*)&tile[r * 260 + col] = w;
  }
  __syncthreads();

  // Phase B: per pass a wave covers 4 channels x 128 rows (256 B each).
  const int wv = threadIdx.x >> 6;  // 0..7
  const int l  = threadIdx.x & 63;
  const int m  = l & 15;            // 8-row block 0..15
  const int c4 = l >> 4;            // 0..3
#pragma unroll
  for (int p = 0; p < 8; ++p) {
    const int ch = wv * 32 + p * 4 + c4;
    u16x8 v;
#pragma unroll
    for (int j = 0; j < 8; ++j) {
      const int r = m * 8 + j;
      v[j] = tile[r * 260 + (ch ^ (m << 2))];
    }
    *(u16x8*)&LRt[(size_t)ch * nslice + (size_t)tn * 128 + m * 8] = v;
  }
}

// ---------------------------------------------------------------------------
// K2: per-channel code gather, 64 KB table in LDS, 512 threads, 2 blocks/CU.
// 32768 elements per block; 8 x u16x8 input loads issued BEFORE table staging
// so HBM latency overlaps the stage.  blockIdx&255 = channel -> all blocks of
// a channel land on the same XCD (c mod 8), table stays L2-resident.
// ---------------------------------------------------------------------------
__global__ __launch_bounds__(512, 4) void code_gather_kernel(
    const unsigned short* __restrict__ LRt, const unsigned char* __restrict__ tab8,
    unsigned char* __restrict__ codes, int nslice) {
  __shared__ unsigned char tabs[KK * KK];  // 64 KB
  const int c   = blockIdx.x & (CCH - 1);
  const int sub = blockIdx.x >> 8;
  const size_t base = (size_t)c * nslice + (size_t)sub * 32768;
  const u16x8* __restrict__ in   = (const u16x8*)(LRt + base);
  uint2*       __restrict__ outp = (uint2*)(codes + base);

  // Issue all 8 input loads first (128 B/thread in flight).
  u16x8 v0 = in[0 * 512 + threadIdx.x];
  u16x8 v1 = in[1 * 512 + threadIdx.x];
  u16x8 v2 = in[2 * 512 + threadIdx.x];
  u16x8 v3 = in[3 * 512 + threadIdx.x];
  u16x8 v4 = in[4 * 512 + threadIdx.x];
  u16x8 v5 = in[5 * 512 + threadIdx.x];
  u16x8 v6 = in[6 * 512 + threadIdx.x];
  u16x8 v7 = in[7 * 512 + threadIdx.x];

  // Stage table (overlaps with the input loads above).
  {
    const int4* src = (const int4*)(tab8 + (size_t)c * (KK * KK));
    int4* dst = (int4*)tabs;
#pragma unroll
    for (int i = 0; i < 8; ++i) dst[i * 512 + threadIdx.x] = src[i * 512 + threadIdx.x];
  }
  __syncthreads();

#define PACK8(v, slot)                                                          \
  {                                                                             \
    unsigned lo = (unsigned)tabs[v[0]] | ((unsigned)tabs[v[1]] << 8) |          \
                  ((unsigned)tabs[v[2]] << 16) | ((unsigned)tabs[v[3]] << 24);  \
    unsigned hi = (unsigned)tabs[v[4]] | ((unsigned)tabs[v[5]] << 8) |          \
                  ((unsigned)tabs[v[6]] << 16) | ((unsigned)tabs[v[7]] << 24);  \
    outp[slot * 512 + threadIdx.x] = make_uint2(lo, hi);                        \
  }
  PACK8(v0, 0) PACK8(v1, 1) PACK8(v2, 2) PACK8(v3, 3)
  PACK8(v4, 4) PACK8(v5, 5) PACK8(v6, 6) PACK8(v7, 7)
#undef PACK8
}

// ---------------------------------------------------------------------------
// K3: codebook + transpose back.  codes [C,nslice] u8 -> out [N,C] f32.
// Tile = 512n x 64ch; LDS = 64 KB codebook slice + 33 KB pitched code tile
// (pitch 129 dwords -> gather-phase reads are 2-way, free).  Store
// instruction covers 64 consecutive channels = 256 B segment; the 4
// channel-group blocks are adjacent in blockIdx (different XCDs) and fill
// each 1 KB output row concurrently.  NT stores: output is never re-read.
// ---------------------------------------------------------------------------
__global__ __launch_bounds__(512, 2) void codebook_transpose_kernel(
    const unsigned char* __restrict__ codes, const float* __restrict__ cb,
    float* __restrict__ out, int n0_base, int nslice) {
  __shared__ float    cbs[64 * KK];    // 64 KB
  __shared__ unsigned ctile[64 * 129]; // 33 KB, pitch 129 dwords
  const int cg = blockIdx.x & 3;
  const int tn = blockIdx.x >> 2;
  const int c0 = cg * 64;

  // Stage codebook slice (16384 f32).
  {
    const f32x4* cbg = (const f32x4*)(cb + (size_t)c0 * KK);
    f32x4* cbl = (f32x4*)cbs;
#pragma unroll
    for (int i = 0; i < 8; ++i) cbl[i * 512 + threadIdx.x] = cbg[i * 512 + threadIdx.x];
  }
  // Stage code tile: 64 ch x 512 B.  8 threads/ch; per instr a wave reads
  // 8 x 128 B segments (L3-resident: codes just written by K2).
  {
    const int cc = threadIdx.x >> 3;  // 0..63
    const int s  = threadIdx.x & 7;   // 0..7
    const unsigned char* srow = codes + (size_t)(c0 + cc) * nslice + (size_t)tn * 512;
#pragma unroll
    for (int k = 0; k < 4; ++k) {
      uint4 val = *(const uint4*)(srow + s * 16 + k * 128);
      const int d0 = cc * 129 + k * 32 + s * 4;
      ctile[d0 + 0] = val.x;
      ctile[d0 + 1] = val.y;
      ctile[d0 + 2] = val.z;
      ctile[d0 + 3] = val.w;
    }
  }
  __syncthreads();

  const int l = threadIdx.x & 63;  // channel lane
  const int w = threadIdx.x >> 6;  // 0..7
  const float* cbrow = cbs + l * KK;
  float* ob = out + (size_t)(n0_base + tn * 512) * CCH + c0 + l;
#pragma unroll
  for (int it = 0; it < 16; ++it) {
    const int n4 = it * 8 + w;                 // 0..127 (quad of rows)
    const unsigned cw = ctile[l * 129 + n4];   // 4 codes
#pragma unroll
    for (int k = 0; k < 4; ++k) {
      const float vv = cbrow[(cw >> (8 * k)) & 255u];
      __builtin_nontemporal_store(vv, ob + (size_t)(n4 * 4 + k) * CCH);
    }
  }
}

// ---------------------------------------------------------------------------
// Fallback: TA-path gather, used only if workspace is tiny.
// ---------------------------------------------------------------------------
#define ROWS_PER_BLOCK 512
#define NGROUPS 16
#define GCH (CCH / NGROUPS)

template <typename TabT>
__global__ __launch_bounds__(256, 8) void gather_kernel(
    const i32x4* __restrict__ left, const i32x4* __restrict__ right,
    const TabT* __restrict__ tab, const float* __restrict__ cb,
    f32x4* __restrict__ out, int nrows) {
  __shared__ float cbs[GCH * KK];
  const int g     = blockIdx.x & (NGROUPS - 1);
  const int chunk = blockIdx.x / NGROUPS;
  const int q     = threadIdx.x & 3;
  const int rsub  = threadIdx.x >> 2;
  {
    const f32x4* cbg = (const f32x4*)(cb + (size_t)(g * GCH) * KK);
    f32x4* cbl = (f32x4*)cbs;
#pragma unroll
    for (int i = 0; i < 4; ++i) cbl[threadIdx.x + i * 256] = cbg[threadIdx.x + i * 256];
  }
  __syncthreads();
  const int cbase  = g * GCH + q * 4;
  const TabT* t0   = tab + (size_t)cbase * (KK * KK);
  const int vecoff = g * 4 + q;
  const float* cq  = cbs + (q * 4) * KK;
  const int rbase = chunk * ROWS_PER_BLOCK;
#pragma unroll
  for (int it = 0; it < ROWS_PER_BLOCK / 32; ++it) {
    const int r0 = rbase + it * 32 + rsub;
    if (r0 >= nrows) break;
    const unsigned v0 = (unsigned)r0 * 64u + (unsigned)vecoff;
    i32x4 L0 = left[v0];
    i32x4 R0 = right[v0];
    unsigned c0 = (unsigned)t0[          (unsigned)(L0[0] * KK + R0[0])];
    unsigned c1 = (unsigned)t0[ 65536u + (unsigned)(L0[1] * KK + R0[1])];
    unsigned c2 = (unsigned)t0[131072u + (unsigned)(L0[2] * KK + R0[2])];
    unsigned c3 = (unsigned)t0[196608u + (unsigned)(L0[3] * KK + R0[3])];
    f32x4 o;
    o[0] = cq[       c0];
    o[1] = cq[KK   + c1];
    o[2] = cq[2*KK + c2];
    o[3] = cq[3*KK + c3];
    out[v0] = o;
  }
}

extern "C" void kernel_launch(void* const* d_in, const int* in_sizes, int n_in,
                              void* d_out, int out_size, void* d_ws, size_t ws_size,
                              hipStream_t stream) {
  const int*   left  = (const int*)d_in[0];
  const int*   right = (const int*)d_in[1];
  const int*   wt    = (const int*)d_in[2];   // [C, K, K] int32
  const float* cb    = (const float*)d_in[3]; // [C, K] float32
  float* out = (float*)d_out;

  const int nrows = in_sizes[0] / CCH;        // 262144
  const int tab_elems = CCH * KK * KK;        // 16,777,216
  const size_t tab_bytes = (size_t)tab_elems; // u8 table = 16 MB

  // Pick smallest slicing S whose workspace fits:
  //   need = 16 MB table + 512*nslice (LRt u16) + 256*nslice (codes u8)
  // Kernel divisibility requires nslice % 32768 == 0.
  int S = 0;
  for (int s = 1; s <= 8; s <<= 1) {
    if (nrows % (s * 32768)) continue;
    size_t need = tab_bytes + (size_t)768 * (size_t)(nrows / s);
    if (need <= ws_size) { S = s; break; }
  }

  if (S) {
    unsigned char* tab8 = (unsigned char*)d_ws;
    int n4 = tab_elems / 4;
    compress_table_kernel<<<n4 / 256, 256, 0, stream>>>(
        (const int4*)wt, (uchar4*)tab8, n4);

    const int nslice = nrows / S;
    unsigned short* LRt = (unsigned short*)((char*)d_ws + tab_bytes);
    unsigned char* codes = (unsigned char*)d_ws + tab_bytes + (size_t)512 * nslice;

    for (int h = 0; h < S; ++h) {
      const int n0 = h * nslice;
      transpose_pack_kernel<<<nslice / 128, 512, 0, stream>>>(
          (const i32x4*)left, (const i32x4*)right, LRt, n0, nslice);
      code_gather_kernel<<<(nslice / 32768) * CCH, 512, 0, stream>>>(
          LRt, tab8, codes, nslice);
      codebook_transpose_kernel<<<(nslice / 512) * 4, 512, 0, stream>>>(
          codes, cb, out, n0, nslice);
    }
  } else if (ws_size >= tab_bytes) {
    unsigned char* tab8 = (unsigned char*)d_ws;
    int n4 = tab_elems / 4;
    compress_table_kernel<<<n4 / 256, 256, 0, stream>>>(
        (const int4*)wt, (uchar4*)tab8, n4);
    const int blocks = ((nrows + ROWS_PER_BLOCK - 1) / ROWS_PER_BLOCK) * NGROUPS;
    gather_kernel<unsigned char><<<blocks, 256, 0, stream>>>(
        (const i32x4*)left, (const i32x4*)right, tab8, cb, (f32x4*)out, nrows);
  } else {
    const int blocks = ((nrows + ROWS_PER_BLOCK - 1) / ROWS_PER_BLOCK) * NGROUPS;
    gather_kernel<int><<<blocks, 256, 0, stream>>>(
        (const i32x4*)left, (const i32x4*)right, wt, cb, (f32x4*)out, nrows);
  }
}